// Round 4
// baseline (315.270 us; speedup 1.0000x reference)
//
#include <hip/hip_runtime.h>
#include <math.h>

#define N_NODES 50000
#define N_EDGES 800000
#define IN_DIM 128
#define HEADS 8
#define HEAD_DIM 16
#define OUT_DIM 128
#define NEG_SLOPE 0.2f
#define BN_EPS 1e-5f

// ---- workspace layout (bytes) ----
#define WS_FEAT    0u            // 50000*128 f32 = 25,600,000
#define WS_EL      25600000u     // 50000*8 f32   = 1,600,000
#define WS_ER      27200000u     // 1,600,000
#define WS_OFFS    28800000u     // 50001 ints (pad to 200,064)
#define WS_PART    29000064u     // 256 ints
#define WS_DEG     29001088u     // 50176 ints = 200,704
#define WS_CURSOR  29201792u     // 50176 ints = 200,704
#define WS_GSUM    29402496u     // 128 f32
#define WS_GSUMSQ  29403008u     // 128 f32
#define WS_CSRSRC  29403520u     // 800000 ints = 3,200,000
#define ZERO_START WS_DEG
#define ZERO_BYTES (WS_CSRSRC - WS_DEG)   // deg+cursor+gsum+gsumsq

#define NB_SCAN 196              // 196*256 = 50176 >= 50000
#define GEMM_BLOCKS 782          // ceil(50000/64)

// ---------------------------------------------------------------------------
// Histogram: LDS-free, full occupancy.
// ---------------------------------------------------------------------------
__global__ void k_hist(const int* __restrict__ dst, int* __restrict__ deg) {
    int i = blockIdx.x * blockDim.x + threadIdx.x;
    if (i < N_EDGES) atomicAdd(&deg[dst[i]], 1);
}

// ---------------------------------------------------------------------------
// GEMM feat = h @ W, 64-row tiles, W staged in LDS (two 32 KB phases),
// fused el/er epilogue. LDS 65.9 KB -> 2 blocks/CU.
// ---------------------------------------------------------------------------
__global__ __launch_bounds__(256) void k_gemm(
    const float* __restrict__ hin, const float* __restrict__ W,
    const float* __restrict__ attn_l, const float* __restrict__ attn_r,
    float* __restrict__ feat, float* __restrict__ el, float* __restrict__ er)
{
    __shared__ float Ws[64 * 128];   // 32 KB (one k-phase of W)
    __shared__ float Hs[64 * 132];   // 33.8 KB
    const int t = threadIdx.x;
    const int row0 = blockIdx.x * 64;

    {   // load 64x128 H tile as float4 (8 per thread)
        const float4* h4 = (const float4*)hin;
        #pragma unroll
        for (int i = 0; i < 8; i++) {
            int idx = t + 256 * i;            // 0..2047
            int r = idx >> 5, c4 = idx & 31;
            int gr = row0 + r;
            float4 v = make_float4(0.f, 0.f, 0.f, 0.f);
            if (gr < N_NODES) v = h4[gr * 32 + c4];
            *(float4*)&Hs[r * 132 + c4 * 4] = v;
        }
    }

    const int tx = t & 15, ty = t >> 4;
    const int c0 = tx * 8, r0 = ty * 4;

    float acc[4][8];
    #pragma unroll
    for (int r = 0; r < 4; r++)
        #pragma unroll
        for (int j = 0; j < 8; j++) acc[r][j] = 0.f;

    const float4* A0 = (const float4*)&Hs[(r0 + 0) * 132];
    const float4* A1 = (const float4*)&Hs[(r0 + 1) * 132];
    const float4* A2 = (const float4*)&Hs[(r0 + 2) * 132];
    const float4* A3 = (const float4*)&Hs[(r0 + 3) * 132];
    const float4* Ws4 = (const float4*)Ws;

    for (int kp = 0; kp < 2; kp++) {
        __syncthreads();   // previous phase consumed / Hs visible
        {
            const float4* w4 = (const float4*)(W + kp * 64 * 128);
            float4* d4 = (float4*)Ws;
            #pragma unroll
            for (int i = 0; i < 8; i++) d4[t + 256 * i] = w4[t + 256 * i];
        }
        __syncthreads();

        #pragma unroll 4
        for (int k4 = 0; k4 < 16; k4++) {     // 64 k this phase, chunks of 4
            float4 a0 = A0[kp * 16 + k4];
            float4 a1 = A1[kp * 16 + k4];
            float4 a2 = A2[kp * 16 + k4];
            float4 a3 = A3[kp * 16 + k4];
            float Av0[4] = {a0.x, a0.y, a0.z, a0.w};
            float Av1[4] = {a1.x, a1.y, a1.z, a1.w};
            float Av2[4] = {a2.x, a2.y, a2.z, a2.w};
            float Av3[4] = {a3.x, a3.y, a3.z, a3.w};
            #pragma unroll
            for (int kk = 0; kk < 4; kk++) {
                float4 b0 = Ws4[(k4 * 4 + kk) * 32 + tx * 2];
                float4 b1 = Ws4[(k4 * 4 + kk) * 32 + tx * 2 + 1];
                float av[4] = {Av0[kk], Av1[kk], Av2[kk], Av3[kk]};
                #pragma unroll
                for (int r = 0; r < 4; r++) {
                    acc[r][0] += av[r] * b0.x; acc[r][1] += av[r] * b0.y;
                    acc[r][2] += av[r] * b0.z; acc[r][3] += av[r] * b0.w;
                    acc[r][4] += av[r] * b1.x; acc[r][5] += av[r] * b1.y;
                    acc[r][6] += av[r] * b1.z; acc[r][7] += av[r] * b1.w;
                }
            }
        }
    }

    // el/er epilogue: cols c0..c0+7 live in head h = tx>>1, half dbase
    const int h = tx >> 1;
    const int dbase = (tx & 1) * 8;
    float elv[4], erv[4];
    #pragma unroll
    for (int r = 0; r < 4; r++) {
        float e = 0.f, f = 0.f;
        #pragma unroll
        for (int j = 0; j < 8; j++) {
            float al = attn_l[h * 16 + dbase + j];
            float ar = attn_r[h * 16 + dbase + j];
            e += acc[r][j] * al; f += acc[r][j] * ar;
        }
        elv[r] = e + __shfl_xor(e, 1);
        erv[r] = f + __shfl_xor(f, 1);
    }

    #pragma unroll
    for (int r = 0; r < 4; r++) {
        int gr = row0 + r0 + r;
        if (gr < N_NODES) {
            *(float4*)&feat[gr * 128 + c0] =
                make_float4(acc[r][0], acc[r][1], acc[r][2], acc[r][3]);
            *(float4*)&feat[gr * 128 + c0 + 4] =
                make_float4(acc[r][4], acc[r][5], acc[r][6], acc[r][7]);
            if ((tx & 1) == 0) { el[gr * 8 + h] = elv[r]; er[gr * 8 + h] = erv[r]; }
        }
    }
}

// ---------------------------------------------------------------------------
// Single-kernel exclusive scan of deg -> offsets (196 blocks).
// ---------------------------------------------------------------------------
__global__ __launch_bounds__(256) void k_scan(const int* __restrict__ deg,
                                              int* __restrict__ offsets)
{
    int t = threadIdx.x, b = blockIdx.x;

    int pre = 0;
    if (t < b) {
        const int4* d4 = (const int4*)(deg + t * 256);
        #pragma unroll 8
        for (int j = 0; j < 64; j++) {
            int4 v = d4[j];
            pre += v.x + v.y + v.z + v.w;
        }
    }
    __shared__ int red[256];
    red[t] = pre;
    __syncthreads();
    #pragma unroll
    for (int o = 128; o > 0; o >>= 1) {
        if (t < o) red[t] += red[t + o];
        __syncthreads();
    }
    int base = red[0];

    __shared__ int buf[2][256];
    int i = b * 256 + t;
    int x = deg[i];
    buf[0][t] = x;
    __syncthreads();
    int pi = 0;
    for (int o = 1; o < 256; o <<= 1) {
        int v = buf[pi][t] + ((t >= o) ? buf[pi][t - o] : 0);
        buf[pi ^ 1][t] = v; pi ^= 1;
        __syncthreads();
    }
    int incl = buf[pi][t];
    if (i < N_NODES) offsets[i] = incl - x + base;
    if (b == NB_SCAN - 1 && t == 255) offsets[N_NODES] = incl + base;
}

// ---------------------------------------------------------------------------
// Lean CSR scatter.
// ---------------------------------------------------------------------------
__global__ void k_scatter(const int* __restrict__ src, const int* __restrict__ dst,
                          const int* __restrict__ offsets, int* __restrict__ cursor,
                          int* __restrict__ csr_src)
{
    int i = blockIdx.x * blockDim.x + threadIdx.x;
    if (i < N_EDGES) {
        int d = dst[i];
        int pos = offsets[d] + atomicAdd(&cursor[d], 1);
        csr_src[pos] = src[i];
    }
}

// ---------------------------------------------------------------------------
// Fused softmax-aggregate: 2 waves per node (edge range split in half),
// combined through LDS. lane owns dims {2l,2l+1}; head h = l>>3.
// ---------------------------------------------------------------------------
__global__ __launch_bounds__(256) void k_agg(
    const float* __restrict__ feat, const float* __restrict__ el,
    const float* __restrict__ er, const int* __restrict__ offsets,
    const int* __restrict__ csr_src, float* __restrict__ outf)
{
    __shared__ float4 comb[2][64];
    int t = threadIdx.x;
    int lane = t & 63;
    int wid = t >> 6;
    int pair = wid >> 1, half = wid & 1;
    int n = blockIdx.x * 2 + pair;            // grid = 25000 -> n < 50000 always
    int h = lane >> 3;
    int start = offsets[n], end = offsets[n + 1];
    int mid = (start + end + 1) >> 1;
    int p  = half ? mid : start;
    int pE = half ? end : mid;
    float er_nh = er[n * 8 + h];
    const float2* feat2 = (const float2*)feat;

    float sum = 0.f, ax = 0.f, ay = 0.f;
    for (; p + 4 <= pE; p += 4) {
        int s0 = csr_src[p + 0], s1 = csr_src[p + 1];
        int s2 = csr_src[p + 2], s3 = csr_src[p + 3];
        float e0 = el[s0 * 8 + h] + er_nh;
        float e1 = el[s1 * 8 + h] + er_nh;
        float e2 = el[s2 * 8 + h] + er_nh;
        float e3 = el[s3 * 8 + h] + er_nh;
        e0 = e0 > 0.f ? e0 : NEG_SLOPE * e0;
        e1 = e1 > 0.f ? e1 : NEG_SLOPE * e1;
        e2 = e2 > 0.f ? e2 : NEG_SLOPE * e2;
        e3 = e3 > 0.f ? e3 : NEG_SLOPE * e3;
        float a0 = __expf(e0), a1 = __expf(e1), a2 = __expf(e2), a3 = __expf(e3);
        float2 f0 = feat2[s0 * 64 + lane];
        float2 f1 = feat2[s1 * 64 + lane];
        float2 f2 = feat2[s2 * 64 + lane];
        float2 f3 = feat2[s3 * 64 + lane];
        sum += (a0 + a1) + (a2 + a3);
        ax += a0 * f0.x; ay += a0 * f0.y;
        ax += a1 * f1.x; ay += a1 * f1.y;
        ax += a2 * f2.x; ay += a2 * f2.y;
        ax += a3 * f3.x; ay += a3 * f3.y;
    }
    for (; p < pE; p++) {
        int s = csr_src[p];
        float e = el[s * 8 + h] + er_nh;
        e = e > 0.f ? e : NEG_SLOPE * e;
        float a = __expf(e);
        float2 f = feat2[s * 64 + lane];
        sum += a; ax += a * f.x; ay += a * f.y;
    }

    if (half == 1) comb[pair][lane] = make_float4(ax, ay, sum, 0.f);
    __syncthreads();
    if (half == 0) {
        float4 o = comb[pair][lane];
        ax += o.x; ay += o.y; sum += o.z;
        float rden = sum > 0.f ? 1.f / sum : 0.f;
        ((float2*)outf)[n * 64 + lane] = make_float2(ax * rden, ay * rden);
    }
}

__global__ __launch_bounds__(256) void k_bnred(const float* __restrict__ outf,
                                               float* __restrict__ gsum,
                                               float* __restrict__ gsumsq) {
    int t = threadIdx.x, b = blockIdx.x;
    int c = t & 127, half = t >> 7;
    const int rows_per = (N_NODES + 255) / 256;
    int r0 = b * rows_per;
    int r1 = r0 + rows_per; if (r1 > N_NODES) r1 = N_NODES;
    float s = 0.f, s2 = 0.f;
    for (int r = r0 + half; r < r1; r += 2) {
        float v = outf[r * 128 + c];
        s += v; s2 += v * v;
    }
    __shared__ float ls[128], ls2[128];
    if (half == 1) { ls[c] = s; ls2[c] = s2; }
    __syncthreads();
    if (half == 0) {
        s += ls[c]; s2 += ls2[c];
        atomicAdd(&gsum[c], s);
        atomicAdd(&gsumsq[c], s2);
    }
}

__global__ __launch_bounds__(256) void k_final(
    const float* __restrict__ hin, const float* __restrict__ gsum,
    const float* __restrict__ gsumsq, const float* __restrict__ gamma,
    const float* __restrict__ beta, float* __restrict__ out)
{
    int i = blockIdx.x * blockDim.x + threadIdx.x;
    if (i >= N_NODES * 32) return;
    int c4 = i & 31;
    float4 x  = ((const float4*)out)[i];
    float4 hv = ((const float4*)hin)[i];
    float4 sm = ((const float4*)gsum)[c4];
    float4 sq = ((const float4*)gsumsq)[c4];
    float4 g  = ((const float4*)gamma)[c4];
    float4 bt = ((const float4*)beta)[c4];
    const float invN = 1.0f / (float)N_NODES;

    float mean, var, rstd, y;
    mean = sm.x * invN; var = sq.x * invN - mean * mean; rstd = rsqrtf(var + BN_EPS);
    y = g.x * (x.x - mean) * rstd + bt.x; y = y > 0.f ? y : (__expf(y) - 1.f); x.x = hv.x + y;
    mean = sm.y * invN; var = sq.y * invN - mean * mean; rstd = rsqrtf(var + BN_EPS);
    y = g.y * (x.y - mean) * rstd + bt.y; y = y > 0.f ? y : (__expf(y) - 1.f); x.y = hv.y + y;
    mean = sm.z * invN; var = sq.z * invN - mean * mean; rstd = rsqrtf(var + BN_EPS);
    y = g.z * (x.z - mean) * rstd + bt.z; y = y > 0.f ? y : (__expf(y) - 1.f); x.z = hv.z + y;
    mean = sm.w * invN; var = sq.w * invN - mean * mean; rstd = rsqrtf(var + BN_EPS);
    y = g.w * (x.w - mean) * rstd + bt.w; y = y > 0.f ? y : (__expf(y) - 1.f); x.w = hv.w + y;

    ((float4*)out)[i] = x;
}

extern "C" void kernel_launch(void* const* d_in, const int* in_sizes, int n_in,
                              void* d_out, int out_size, void* d_ws, size_t ws_size,
                              hipStream_t stream)
{
    const float* hin    = (const float*)d_in[0];
    const int*   src    = (const int*)d_in[1];
    const int*   dst    = (const int*)d_in[2];
    const float* W      = (const float*)d_in[3];
    const float* attn_l = (const float*)d_in[4];
    const float* attn_r = (const float*)d_in[5];
    const float* gamma  = (const float*)d_in[6];
    const float* beta   = (const float*)d_in[7];
    float* out = (float*)d_out;

    char* ws = (char*)d_ws;
    float* feat    = (float*)(ws + WS_FEAT);
    float* el      = (float*)(ws + WS_EL);
    float* er      = (float*)(ws + WS_ER);
    int*   offsets = (int*)(ws + WS_OFFS);
    int*   deg     = (int*)(ws + WS_DEG);
    int*   cursor  = (int*)(ws + WS_CURSOR);
    float* gsum    = (float*)(ws + WS_GSUM);
    float* gsumsq  = (float*)(ws + WS_GSUMSQ);
    int*   csr     = (int*)(ws + WS_CSRSRC);

    hipMemsetAsync(ws + ZERO_START, 0, ZERO_BYTES, stream);
    k_hist<<<(N_EDGES + 255) / 256, 256, 0, stream>>>(dst, deg);
    k_gemm<<<GEMM_BLOCKS, 256, 0, stream>>>(hin, W, attn_l, attn_r, feat, el, er);
    k_scan<<<NB_SCAN, 256, 0, stream>>>(deg, offsets);
    k_scatter<<<(N_EDGES + 255) / 256, 256, 0, stream>>>(src, dst, offsets, cursor, csr);
    k_agg<<<N_NODES / 2, 256, 0, stream>>>(feat, el, er, offsets, csr, out);
    k_bnred<<<256, 256, 0, stream>>>(out, gsum, gsumsq);
    k_final<<<(N_NODES * 32) / 256, 256, 0, stream>>>(hin, gsum, gsumsq, gamma, beta, out);
}